// Round 2
// baseline (298.009 us; speedup 1.0000x reference)
//
#include <hip/hip_runtime.h>
#include <hip/hip_bf16.h>

typedef __attribute__((ext_vector_type(8))) short short8;
typedef __attribute__((ext_vector_type(4))) float f32x4;

#define MFMA16(a,b,c) __builtin_amdgcn_mfma_f32_16x16x32_bf16((a),(b),(c),0,0,0)

static __device__ __forceinline__ float b2f(ushort u){
  union { unsigned u32; float f; } x; x.u32 = ((unsigned)u) << 16; return x.f;
}
static __device__ __forceinline__ ushort f2b(float f){
  union { float f; unsigned u; } x; x.f = f;
  unsigned r = x.u + 0x7fffu + ((x.u >> 16) & 1u);
  return (ushort)(r >> 16);
}
// flag-aware input load: bf=1 -> bf16, bf=0 -> f32
static __device__ __forceinline__ float ldin(const void* p, size_t i, int bf){
  return bf ? b2f(((const ushort*)p)[i]) : ((const float*)p)[i];
}
// NaN-PROPAGATING relu (fmaxf(NaN,0)==0 would mask upstream NaNs)
static __device__ __forceinline__ float relu(float v){ return (v <= 0.f) ? 0.f : v; }

// ---------------- K0: dtype probe (sp_gamma==1.0) + zero BN accumulators -----
__global__ void k_init(const ushort* g, int* flag, float* stats){
  int t = threadIdx.x;
  if(t == 0) *flag = (g[0] == 0x3F80) ? 1 : 0;   // bf16 1.0 = 0x3F80; f32 1.0 low half = 0x0000
  stats[t] = 0.f;                                 // 256 floats
}

// ---------------- K0b: convert sp_w -> bf16 arena ----------------------------
__global__ __launch_bounds__(256) void k_cvtw(const void* src, ushort* dst, const int* flag){
  int bf = *flag;
  int i = blockIdx.x * 256 + threadIdx.x;         // 524288 total
  dst[i] = bf ? ((const ushort*)src)[i] : f2b(((const float*)src)[i]);
}

// ---------------- K1: kNN (top-2 smallest dist) + inverse-distance weights ---
__global__ __launch_bounds__(256) void k_knn(const void* __restrict__ bef,
    const void* __restrict__ coor, int* __restrict__ idx, float* __restrict__ wgt,
    const int* __restrict__ flag){
  int bf = *flag;
  int t = blockIdx.x * 256 + threadIdx.x;   // 0..2047
  int b = t >> 6;
  float v[32]; float sb = 0.f;
  size_t broff = (size_t)t * 32;
  #pragma unroll
  for(int c=0;c<32;c++){ float x = ldin(bef, broff + c, bf); v[c] = x; sb += x*x; }
  float d0 = 1e30f, d1 = 1e30f; int i0 = 0, i1 = 0;
  size_t croff = (size_t)b * 1024;
  for(int m=0;m<32;m++){
    float dot = 0.f, sc = 0.f;
    #pragma unroll
    for(int c=0;c<32;c++){ float x = ldin(coor, croff + m*32 + c, bf); dot += v[c]*x; sc += x*x; }
    float d = sb + sc - 2.f*dot;
    if(d < d0){ d1 = d0; i1 = i0; d0 = d; i0 = m; }      // strict < keeps lowest index on ties
    else if(d < d1){ d1 = d; i1 = m; }
  }
  float r0 = 1.f/(d0 + 1e-8f), r1 = 1.f/(d1 + 1e-8f);
  float sum = r0 + r1;
  idx[t*2] = i0; idx[t*2+1] = i1;
  wgt[t*2] = r0/sum; wgt[t*2+1] = r1/sum;
}

// ---------------- K2: build conv weight matrices A_even/A_odd [128 o][512 kc] -
// ct_w: [256 in][128 out][1][4]. A_even = [kw1 ; kw3], A_odd = [kw0 ; kw2]
__global__ void k_build_A(const void* __restrict__ ctw,
    ushort* __restrict__ Aev, ushort* __restrict__ Aod, const int* __restrict__ flag){
  int bf = *flag;
  int i = blockIdx.x * 256 + threadIdx.x;   // 0..65535 = o*512 + kc
  int o = i >> 9, kc = i & 511;
  int c = kc & 255; int hi = (kc >= 256);
  size_t base = ((size_t)c*128 + o)*4;
  Aev[i] = f2b(ldin(ctw, base + (hi ? 3 : 1), bf));
  Aod[i] = f2b(ldin(ctw, base + (hi ? 2 : 0), bf));
}

// ---------------- K3: sparse interpolation, transposed: spiT[b][n][c] ---------
__global__ __launch_bounds__(256) void k_spiT(const void* __restrict__ sf,
    const int* __restrict__ idx, const float* __restrict__ wgt, ushort* __restrict__ spiT,
    const int* __restrict__ flag){
  int bf = *flag;
  int bn = blockIdx.x;               // b*64+n
  int b = bn >> 6;
  int i0 = idx[bn*2], i1 = idx[bn*2+1];
  float w0 = wgt[bn*2], w1 = wgt[bn*2+1];
  size_t base = (size_t)b*1024*32;   // [c][32 strokes]
  ushort* o = spiT + (size_t)bn*1024;
  for(int c = threadIdx.x; c < 1024; c += 256){
    float v = w0 * ldin(sf, base + c*32 + i0, bf) + w1 * ldin(sf, base + c*32 + i1, bf);
    o[c] = f2b(v);
  }
}

// ---------------- K4: sparse GEMM h[o][b*64+n] = sp_w @ spiT_b + bias ---------
__global__ __launch_bounds__(256) void k_sgemm(const ushort* __restrict__ spw,
    const ushort* __restrict__ spiT, const void* __restrict__ spb,
    float* __restrict__ h, const int* __restrict__ flag){
  int bf = *flag;
  int blk = blockIdx.x; int b = blk >> 3, og = blk & 7;
  int wave = threadIdx.x >> 6, lane = threadIdx.x & 63;
  int lo = lane & 15, hi = lane >> 4;
  int o0 = og*64 + wave*16;
  const short* A = (const short*)spw  + (size_t)(o0 + lo)*1024 + hi*8;
  const short* B = (const short*)spiT + (size_t)(b*64 + lo)*1024 + hi*8;
  f32x4 acc[4] = {};
  for(int k = 0; k < 1024; k += 32){
    short8 a = *(const short8*)(A + k);
    #pragma unroll
    for(int q=0;q<4;q++){
      short8 bb = *(const short8*)(B + q*16*1024 + k);
      acc[q] = MFMA16(a, bb, acc[q]);
    }
  }
  #pragma unroll
  for(int q=0;q<4;q++){
    int n = q*16 + lo;
    #pragma unroll
    for(int r=0;r<4;r++){
      int o = o0 + hi*4 + r;
      h[(size_t)o*2048 + b*64 + n] = acc[q][r] + ldin(spb, o, bf);
    }
  }
}

// ---------------- K5: sparse BN (batch stats over b,n) + ReLU -> d_out --------
__global__ __launch_bounds__(256) void k_sbn(const float* __restrict__ h,
    const void* __restrict__ gam, const void* __restrict__ bet,
    void* __restrict__ outp, const int* __restrict__ flag){
  int bf = *flag;
  int o = blockIdx.x;
  const float* row = h + (size_t)o * 2048;
  float s = 0.f, s2 = 0.f;
  for(int j = threadIdx.x; j < 2048; j += 256){ float v = row[j]; s += v; s2 += v*v; }
  #pragma unroll
  for(int off=32; off; off>>=1){ s += __shfl_down(s, off); s2 += __shfl_down(s2, off); }
  __shared__ float ps[4], ps2[4], bc[2];
  int wave = threadIdx.x >> 6, lane = threadIdx.x & 63;
  if(lane == 0){ ps[wave] = s; ps2[wave] = s2; }
  __syncthreads();
  if(threadIdx.x == 0){
    float S = ps[0]+ps[1]+ps[2]+ps[3], S2 = ps2[0]+ps2[1]+ps2[2]+ps2[3];
    float mu = S / 2048.f;
    float var = fmaxf(S2 / 2048.f - mu*mu, 0.f);
    bc[0] = mu; bc[1] = rsqrtf(var + 1e-5f);
  }
  __syncthreads();
  float mu = bc[0], a = ldin(gam, o, bf) * bc[1], be = ldin(bet, o, bf);
  for(int j = threadIdx.x; j < 2048; j += 256){
    float v = relu(a * (row[j] - mu) + be);
    int b = j >> 6, n = j & 63;
    size_t oi = ((size_t)b*512 + o)*64 + n;
    if(bf) ((ushort*)outp)[oi] = f2b(v); else ((float*)outp)[oi] = v;
  }
}

// ---------------- K6: transpose df[b][c][s][p] -> dfT[b][s][p][c] (bf16) ------
__global__ __launch_bounds__(256) void k_tr(const void* __restrict__ df, ushort* __restrict__ dfT,
    const int* __restrict__ flag){
  int bf = *flag;
  __shared__ ushort T[256*66];                 // [c][p] tile, padded stride 66
  int bs_ = blockIdx.x; int b = bs_ >> 5, s = bs_ & 31;
  int wave = threadIdx.x >> 6, lane = threadIdx.x & 63;
  size_t src = ((size_t)b*256*32 + s)*64;      // + c*2048 + p
  for(int k=0;k<64;k++){
    int c = wave*64 + k;
    T[c*66 + lane] = f2b(ldin(df, src + (size_t)c*2048 + lane, bf));
  }
  __syncthreads();
  ushort* dst = dfT + (size_t)bs_*16384;       // [p][c]
  for(int k=0;k<64;k++){
    int p = wave*16 + (k >> 2);
    int c = (k & 3)*64 + lane;
    dst[p*256 + c] = T[c*66 + p];
  }
}

// ---------------- K7: ConvTranspose as 2 GEMMs per (b,s) ---------------------
// LDS L[66][256]: row 0 & 65 zero, row p+1 = dfT[b][s][p][:], XOR-swizzled.
// Y_even[o,t](wo=2t)  = A_ev . [x[:,t] ; x[:,t-1]]
// Y_odd [o,t](wo=2t+1)= A_od . [x[:,t+1]; x[:,t]]
__global__ __launch_bounds__(256) void k_conv(const ushort* __restrict__ dfT,
    const ushort* __restrict__ Aev, const ushort* __restrict__ Aod,
    const void* __restrict__ ctb, ushort* __restrict__ z, const int* __restrict__ flag){
  int bf = *flag;
  __shared__ ushort L[66*256];
  int bs_ = blockIdx.x;
  int tid = threadIdx.x;
  int wave = tid >> 6, lane = tid & 63;
  int lo = lane & 15, hi = lane >> 4;

  { // zero boundary rows 0 and 65 (512B each)
    unsigned* Lw = (unsigned*)L;
    int i = (tid < 128) ? tid : (65*512/4 + (tid - 128));
    Lw[i] = 0u;
  }
  { // stage 64 rows, swizzled writes (read side uses same XOR -> consistent, rule #21)
    const short8* src = (const short8*)(dfT + (size_t)bs_ * 16384);
    #pragma unroll
    for(int j=0;j<8;j++){
      int q = j*256 + tid;            // 0..2047 : 16B chunks
      int r = q >> 5;                 // source row p (0..63)
      int w = q & 31;
      short8 v = src[q];
      int row = r + 1;
      char* p = (char*)L + row*512 + ((w*16) ^ ((row & 7) << 4));
      *(short8*)p = v;
    }
  }
  __syncthreads();

  int o0 = wave * 32;
  const short* Ae = (const short*)Aev + (size_t)(o0 + lo)*512 + hi*8;
  const short* Ao = (const short*)Aod + (size_t)(o0 + lo)*512 + hi*8;
  f32x4 ae_acc[2][4] = {}; f32x4 ao_acc[2][4] = {};

  for(int kc0 = 0; kc0 < 512; kc0 += 32){
    short8 a_e0 = *(const short8*)(Ae + kc0);
    short8 a_e1 = *(const short8*)(Ae + 16*512 + kc0);
    short8 a_o0 = *(const short8*)(Ao + kc0);
    short8 a_o1 = *(const short8*)(Ao + 16*512 + kc0);
    int base_shift = (kc0 < 256) ? 1 : 0;   // L-row for even = t + base_shift
    int kcl = (kc0 & 255) + hi*8;
    #pragma unroll
    for(int q=0;q<4;q++){
      int t = q*16 + lo;
      int re = t + base_shift;          // even-parity source row
      int ro = re + 1;                  // odd-parity source row (max 65 = zero row)
      short8 be = *(const short8*)((char*)L + re*512 + ((2*kcl) ^ ((re & 7) << 4)));
      short8 bo = *(const short8*)((char*)L + ro*512 + ((2*kcl) ^ ((ro & 7) << 4)));
      ae_acc[0][q] = MFMA16(a_e0, be, ae_acc[0][q]);
      ae_acc[1][q] = MFMA16(a_e1, be, ae_acc[1][q]);
      ao_acc[0][q] = MFMA16(a_o0, bo, ao_acc[0][q]);
      ao_acc[1][q] = MFMA16(a_o1, bo, ao_acc[1][q]);
    }
  }

  // epilogue: z[b][o][s][wo], pack (wo=2t, 2t+1) as one u32
  int b = bs_ >> 5, s = bs_ & 31;
  unsigned* zo = (unsigned*)z;
  #pragma unroll
  for(int m=0;m<2;m++){
    #pragma unroll
    for(int q=0;q<4;q++){
      int t = q*16 + lo;
      #pragma unroll
      for(int r=0;r<4;r++){
        int o = o0 + m*16 + hi*4 + r;
        float bias = ldin(ctb, o, bf);
        float ve = ae_acc[m][q][r] + bias;
        float vo = ao_acc[m][q][r] + bias;
        unsigned pk = (unsigned)f2b(ve) | ((unsigned)f2b(vo) << 16);
        zo[ ((size_t)(b*128 + o)*32 + s)*64 + t ] = pk;
      }
    }
  }
}

// ---------------- K8: dense BN batch stats over interpolated y ----------------
__global__ __launch_bounds__(256) void k_dstats(const ushort* __restrict__ z,
    const int* __restrict__ idx, const float* __restrict__ wgt, float* __restrict__ stats){
  int blk = blockIdx.x; int b = blk >> 7, o = blk & 127;
  const ushort* zb = z + ((size_t)(b*128 + o) * 32) * 128;
  int tid = threadIdx.x, wo = tid & 127, nh = tid >> 7;
  float s = 0.f, s2 = 0.f;
  for(int n = nh; n < 64; n += 2){
    int bn = b*64 + n;
    float w0 = wgt[bn*2], w1 = wgt[bn*2+1];
    int i0 = idx[bn*2], i1 = idx[bn*2+1];
    float y = w0 * b2f(zb[i0*128 + wo]) + w1 * b2f(zb[i1*128 + wo]);
    s += y; s2 += y*y;
  }
  #pragma unroll
  for(int off=32; off; off>>=1){ s += __shfl_down(s, off); s2 += __shfl_down(s2, off); }
  __shared__ float ps[4], ps2[4];
  int wave = tid >> 6, lane = tid & 63;
  if(lane == 0){ ps[wave] = s; ps2[wave] = s2; }
  __syncthreads();
  if(tid == 0){
    atomicAdd(&stats[o*2],   ps[0]+ps[1]+ps[2]+ps[3]);
    atomicAdd(&stats[o*2+1], ps2[0]+ps2[1]+ps2[2]+ps2[3]);
  }
}

// ---------------- K9: dense normalize + ReLU -> d_out -------------------------
__global__ __launch_bounds__(256) void k_dout(const ushort* __restrict__ z,
    const int* __restrict__ idx, const float* __restrict__ wgt,
    const float* __restrict__ stats, const void* __restrict__ gam,
    const void* __restrict__ bet, void* __restrict__ outp, const int* __restrict__ flag){
  int bf = *flag;
  int blk = blockIdx.x; int b = blk >> 7, o = blk & 127;
  const float N = 262144.f;
  float S = stats[o*2], S2 = stats[o*2+1];
  float mu = S / N;
  float var = fmaxf(S2 / N - mu*mu, 0.f);
  float a = ldin(gam, o, bf) * rsqrtf(var + 1e-5f);
  float be = ldin(bet, o, bf);
  const ushort* zb = z + ((size_t)(b*128 + o) * 32) * 128;
  size_t obase = 1048576 + ((size_t)(b*128 + o) * 64) * 128;
  int tid = threadIdx.x, wo = tid & 127, nh = tid >> 7;
  for(int n = nh; n < 64; n += 2){
    int bn = b*64 + n;
    float w0 = wgt[bn*2], w1 = wgt[bn*2+1];
    int i0 = idx[bn*2], i1 = idx[bn*2+1];
    float y = w0 * b2f(zb[i0*128 + wo]) + w1 * b2f(zb[i1*128 + wo]);
    float v = relu(a * (y - mu) + be);
    size_t oi = obase + n*128 + wo;
    if(bf) ((ushort*)outp)[oi] = f2b(v); else ((float*)outp)[oi] = v;
  }
}

extern "C" void kernel_launch(void* const* d_in, const int* in_sizes, int n_in,
                              void* d_out, int out_size, void* d_ws, size_t ws_size,
                              hipStream_t stream) {
  (void)in_sizes; (void)n_in; (void)out_size; (void)ws_size;
  const void* sparse_fea = d_in[0];
  const void* dense_fea  = d_in[1];
  const void* stk_coor   = d_in[2];
  const void* stk_bef    = d_in[3];
  const void* sp_w   = d_in[4];
  const void* sp_b   = d_in[5];
  const void* sp_g   = d_in[6];
  const void* sp_be  = d_in[7];
  const void* ct_w   = d_in[8];
  const void* ct_b   = d_in[9];
  const void* bn_g   = d_in[10];
  const void* bn_be  = d_in[11];

  char* ws = (char*)d_ws;
  int*    idx   = (int*)   (ws + 0);            //  16 KB
  float*  wgt   = (float*) (ws + 16384);        //  16 KB
  float*  dst   = (float*) (ws + 32768);        //   1 KB (BN accum, zeroed by k_init)
  int*    flag  = (int*)   (ws + 33792);        //   4 B  (dtype flag)
  ushort* Aev   = (ushort*)(ws + 34816);        // 128 KB
  ushort* Aod   = (ushort*)(ws + 165888);       // 128 KB
  ushort* spwb  = (ushort*)(ws + 296960);       //   1 MB (sp_w as bf16)
  ushort* spiT  = (ushort*)(ws + 1345536);      //   4 MB
  float*  h     = (float*) (ws + 5539840);      //   4 MB
  ushort* dfT   = (ushort*)(ws + 9734144);      //  32 MB
  ushort* z     = (ushort*)(ws + 43288576);     //  32 MB  (total ~76.8 MB)

  // Diagnostic: if kernels never execute, this pattern (bf16 0x3C3C ~= 0.011)
  // shifts the reported absmax away from the exact all-zeros value 4.875000.
  hipMemsetAsync(d_out, 0x3C, 2097152, stream);

  hipLaunchKernelGGL(k_init,    dim3(1),    dim3(256), 0, stream, (const ushort*)sp_g, flag, dst);
  hipLaunchKernelGGL(k_cvtw,    dim3(2048), dim3(256), 0, stream, sp_w, spwb, flag);
  hipLaunchKernelGGL(k_knn,     dim3(8),    dim3(256), 0, stream, stk_bef, stk_coor, idx, wgt, flag);
  hipLaunchKernelGGL(k_build_A, dim3(256),  dim3(256), 0, stream, ct_w, Aev, Aod, flag);
  hipLaunchKernelGGL(k_spiT,    dim3(2048), dim3(256), 0, stream, sparse_fea, idx, wgt, spiT, flag);
  hipLaunchKernelGGL(k_sgemm,   dim3(256),  dim3(256), 0, stream, spwb, spiT, sp_b, h, flag);
  hipLaunchKernelGGL(k_sbn,     dim3(512),  dim3(256), 0, stream, h, sp_g, sp_be, d_out, flag);
  hipLaunchKernelGGL(k_tr,      dim3(1024), dim3(256), 0, stream, dense_fea, dfT, flag);
  hipLaunchKernelGGL(k_conv,    dim3(1024), dim3(256), 0, stream, dfT, Aev, Aod, ct_b, z, flag);
  hipLaunchKernelGGL(k_dstats,  dim3(4096), dim3(256), 0, stream, z, idx, wgt, dst);
  hipLaunchKernelGGL(k_dout,    dim3(4096), dim3(256), 0, stream, z, idx, wgt, dst, bn_g, bn_be, d_out, flag);
}

// Round 3
// 257.852 us; speedup vs baseline: 1.1557x; 1.1557x over previous
//
#include <hip/hip_runtime.h>
#include <hip/hip_bf16.h>

typedef __attribute__((ext_vector_type(8))) short short8;
typedef __attribute__((ext_vector_type(4))) float f32x4;
typedef __attribute__((ext_vector_type(16))) float f32x16;

#define MFMA16(a,b,c) __builtin_amdgcn_mfma_f32_16x16x32_bf16((a),(b),(c),0,0,0)
#define MFMA32(a,b,c) __builtin_amdgcn_mfma_f32_32x32x16_bf16((a),(b),(c),0,0,0)

static __device__ __forceinline__ float b2f(ushort u){
  union { unsigned u32; float f; } x; x.u32 = ((unsigned)u) << 16; return x.f;
}
static __device__ __forceinline__ ushort f2b(float f){
  union { float f; unsigned u; } x; x.f = f;
  unsigned r = x.u + 0x7fffu + ((x.u >> 16) & 1u);
  return (ushort)(r >> 16);
}
// NaN-PROPAGATING relu (fmaxf(NaN,0)==0 would mask upstream NaNs)
static __device__ __forceinline__ float relu(float v){ return (v <= 0.f) ? 0.f : v; }

// ---------------- K1: fused prep: sp_w->bf16 | build A_ev/A_od | kNN ---------
// blocks [0,512): cvt sp_w (524288 f32) as float4
// blocks [512,768): A_even=[kw1;kw3], A_odd=[kw0;kw2], [128 o][512 kc] bf16
// blocks [768,776): kNN top-2 + inverse-distance weights
__global__ __launch_bounds__(256) void k_prep(
    const float* __restrict__ spw, ushort* __restrict__ spwb,
    const float* __restrict__ ctw, ushort* __restrict__ Aev, ushort* __restrict__ Aod,
    const float* __restrict__ bef, const float* __restrict__ coor,
    int* __restrict__ idx, float* __restrict__ wgt){
  int blk = blockIdx.x, tid = threadIdx.x;
  if(blk < 512){
    int i = blk*256 + tid;                  // float4 index, 131072 total
    float4 v = ((const float4*)spw)[i];
    ushort4 o; o.x=f2b(v.x); o.y=f2b(v.y); o.z=f2b(v.z); o.w=f2b(v.w);
    ((ushort4*)spwb)[i] = o;
  } else if(blk < 768){
    int i = (blk-512)*256 + tid;            // 65536 = o*512 + kc
    int o = i >> 9, kc = i & 511;
    int c = kc & 255, hi = kc >> 8;
    const float* w = ctw + ((size_t)c*128 + o)*4;   // [in 256][out 128][1][4]
    Aev[i] = f2b(w[hi ? 3 : 1]);
    Aod[i] = f2b(w[hi ? 2 : 0]);
  } else {
    int t = (blk-768)*256 + tid;            // 0..2047 = b*64+n
    int b = t >> 6;
    float v[32]; float sb = 0.f;
    const float* br = bef + (size_t)t * 32;
    #pragma unroll
    for(int c=0;c<32;c++){ float x = br[c]; v[c] = x; sb += x*x; }
    float d0 = 1e30f, d1 = 1e30f; int i0 = 0, i1 = 0;
    const float* cr = coor + (size_t)b * 1024;
    for(int m=0;m<32;m++){
      float dot = 0.f, sc = 0.f;
      #pragma unroll
      for(int c=0;c<32;c++){ float x = cr[m*32+c]; dot += v[c]*x; sc += x*x; }
      float d = sb + sc - 2.f*dot;
      if(d < d0){ d1 = d0; i1 = i0; d0 = d; i0 = m; }   // strict < keeps lowest idx on ties
      else if(d < d1){ d1 = d; i1 = m; }
    }
    float r0 = 1.f/(d0 + 1e-8f), r1 = 1.f/(d1 + 1e-8f);
    float sum = r0 + r1;
    idx[t*2] = i0; idx[t*2+1] = i1;
    wgt[t*2] = r0/sum; wgt[t*2+1] = r1/sum;
  }
}

// ---------------- K2: sparse interpolation, transposed: spiT[b][n][c] bf16 ----
__global__ __launch_bounds__(256) void k_spiT(const float* __restrict__ sf,
    const int* __restrict__ idx, const float* __restrict__ wgt, ushort* __restrict__ spiT){
  int bn = blockIdx.x;               // b*64+n
  int b = bn >> 6;
  int i0 = idx[bn*2], i1 = idx[bn*2+1];
  float w0 = wgt[bn*2], w1 = wgt[bn*2+1];
  const float* base = sf + (size_t)b*1024*32;   // [c][32 strokes]
  ushort* o = spiT + (size_t)bn*1024;
  for(int c = threadIdx.x; c < 1024; c += 256){
    float v = w0 * base[c*32 + i0] + w1 * base[c*32 + i1];
    o[c] = f2b(v);
  }
}

// ---------------- K3: sparse GEMM h = sp_w @ spiT + bias, fused stat atomics --
// 512 blocks: b(32) x og(8) x nh(2); block covers 64 o x 32 n
__global__ __launch_bounds__(256) void k_sgemm(const ushort* __restrict__ spw,
    const ushort* __restrict__ spiT, const float* __restrict__ spb,
    float* __restrict__ h, float* __restrict__ sstats){
  int blk = blockIdx.x;
  int b = blk >> 4, og = (blk >> 1) & 7, nh = blk & 1;
  int wave = threadIdx.x >> 6, lane = threadIdx.x & 63;
  int lo = lane & 15, hi = lane >> 4;
  int o0 = og*64 + wave*16;
  const short* A = (const short*)spw  + (size_t)(o0 + lo)*1024 + hi*8;
  const short* B = (const short*)spiT + (size_t)(b*64 + nh*32 + lo)*1024 + hi*8;
  f32x4 acc[2] = {};
  for(int k = 0; k < 1024; k += 32){
    short8 a = *(const short8*)(A + k);
    #pragma unroll
    for(int q=0;q<2;q++){
      short8 bb = *(const short8*)(B + q*16*1024 + k);
      acc[q] = MFMA16(a, bb, acc[q]);
    }
  }
  float sv[4], sv2[4], bias[4];
  #pragma unroll
  for(int r=0;r<4;r++){ sv[r]=0.f; sv2[r]=0.f; bias[r] = spb[o0 + hi*4 + r]; }
  #pragma unroll
  for(int q=0;q<2;q++){
    int n = nh*32 + q*16 + lo;
    #pragma unroll
    for(int r=0;r<4;r++){
      int o = o0 + hi*4 + r;
      float val = acc[q][r] + bias[r];
      h[(size_t)o*2048 + b*64 + n] = val;
      sv[r] += val; sv2[r] += val*val;
    }
  }
  #pragma unroll
  for(int r=0;r<4;r++){
    #pragma unroll
    for(int off=1; off<16; off<<=1){
      sv[r]  += __shfl_xor(sv[r],  off);
      sv2[r] += __shfl_xor(sv2[r], off);
    }
  }
  if(lo == 0){
    #pragma unroll
    for(int r=0;r<4;r++){
      int o = o0 + hi*4 + r;
      atomicAdd(&sstats[o*2],   sv[r]);
      atomicAdd(&sstats[o*2+1], sv2[r]);
    }
  }
}

// ---------------- K4: sparse BN normalize + ReLU -> d_out (single pass) -------
__global__ __launch_bounds__(256) void k_sbn(const float* __restrict__ h,
    const float* __restrict__ sstats, const float* __restrict__ gam,
    const float* __restrict__ bet, float* __restrict__ out){
  int o = blockIdx.x;
  float mu = sstats[o*2] / 2048.f;
  float var = fmaxf(sstats[o*2+1] / 2048.f - mu*mu, 0.f);
  float a = gam[o] * rsqrtf(var + 1e-5f);
  float be = bet[o];
  const float* row = h + (size_t)o * 2048;
  #pragma unroll
  for(int it=0; it<2; ++it){
    int j = it*1024 + threadIdx.x*4;
    float4 v = *(const float4*)(row + j);
    float4 r;
    r.x = relu(a*(v.x-mu)+be); r.y = relu(a*(v.y-mu)+be);
    r.z = relu(a*(v.z-mu)+be); r.w = relu(a*(v.w-mu)+be);
    int b = j >> 6, n = j & 63;
    *(float4*)(out + ((size_t)b*512 + o)*64 + n) = r;
  }
}

// ---------------- K5: fused transpose + ConvTranspose GEMMs + z repack --------
// block=(b,s). LDS L[66 rows][256 c] bf16, 512B/row, rows 0&65 zero,
// row p+1 = dense_fea[b][:,s,p] transposed. Swizzle: byte ^= ((row>>2)&7)<<4
// (write AND read sides). Wave = (parity pe, t-tile tt); B-frag reused over
// 4 o-tiles (128 o). Even: Y[o,2t] = A_ev.[x_t;x_{t-1}], Odd: Y[o,2t+1]=A_od.[x_{t+1};x_t]
__global__ __launch_bounds__(256) void k_conv(const float* __restrict__ df,
    const ushort* __restrict__ Aev, const ushort* __restrict__ Aod,
    const float* __restrict__ ctb, ushort* __restrict__ z){
  __shared__ ushort L[66*256];   // 33792 B
  int bs_ = blockIdx.x; int b = bs_ >> 5, s = bs_ & 31;
  int tid = threadIdx.x;

  { // zero boundary rows 0 and 65
    unsigned* Lw = (unsigned*)L;
    int i = (tid < 128) ? tid : (65*128 + (tid - 128));
    Lw[i] = 0u;
  }
  // stage + transpose + f32->bf16: c = it*16 + (tid>>4), p0 = (tid&15)*4
  const float* src = df + ((size_t)(b*256)*32 + s)*64;   // + c*2048 + p
  for(int it=0; it<16; ++it){
    int c = it*16 + (tid>>4);
    float4 v = *(const float4*)(src + (size_t)c*2048 + (tid&15)*4);
    int p0 = (tid&15)*4;
    #pragma unroll
    for(int j=0;j<4;j++){
      int row = p0 + j + 1;
      float fv = (j==0)?v.x:(j==1)?v.y:(j==2)?v.z:v.w;
      *(ushort*)((char*)L + row*512 + ((2*c) ^ (((row>>2)&7)<<4))) = f2b(fv);
    }
  }
  __syncthreads();

  int wave = tid >> 6, lane = tid & 63;
  int pe = wave >> 1, tt = wave & 1;     // parity, t-tile
  int tcol = lane & 31;
  int t = tt*32 + tcol;
  int kl = (lane >> 5) * 8;
  const short* A = (const short*)(pe ? Aod : Aev);
  f32x16 acc[4] = {};
  #pragma unroll
  for(int hf=0; hf<2; ++hf){
    int rowr = t + (hf==0 ? 1 : 0) + pe;       // source L-row for this parity/half
    const char* Lr = (const char*)L + rowr*512;
    int swz = ((rowr>>2)&7) << 4;
    for(int k0=0; k0<256; k0+=16){
      short8 bfrag = *(const short8*)(Lr + ((2*(k0+kl)) ^ swz));
      const short* Ab = A + hf*256 + k0 + kl;
      #pragma unroll
      for(int ot=0; ot<4; ++ot){
        short8 afrag = *(const short8*)(Ab + (size_t)(ot*32 + tcol)*512);
        acc[ot] = MFMA32(afrag, bfrag, acc[ot]);
      }
    }
  }
  __syncthreads();   // all waves done reading L before repack overwrite

  // repack via LDS: Z[o 128][wo 128] bf16 (32 KB, reuse L)
  #pragma unroll
  for(int ot=0; ot<4; ++ot){
    #pragma unroll
    for(int r=0;r<16;r++){
      int o = ot*32 + (r&3) + 8*(r>>2) + 4*(lane>>5);
      L[o*128 + 2*t + pe] = f2b(acc[ot][r] + ctb[o]);
    }
  }
  __syncthreads();
  // linear coalesced store: z[b][o][s][wo]
  ushort* zb = z + ((size_t)(b*128)*32 + s)*128;
  #pragma unroll
  for(int it=0; it<8; ++it){
    int q = it*256 + tid;          // short8 chunk, 2048 total
    int o = q >> 4, w0 = (q & 15)*8;
    *(short8*)(zb + (size_t)o*4096 + w0) = *(const short8*)(L + o*128 + w0);
  }
}

// ---------------- K6: dense BN batch stats over interpolated y ----------------
__global__ __launch_bounds__(256) void k_dstats(const ushort* __restrict__ z,
    const int* __restrict__ idx, const float* __restrict__ wgt, float* __restrict__ stats){
  int blk = blockIdx.x; int b = blk >> 7, o = blk & 127;
  const ushort* zb = z + (size_t)(b*128 + o) * 4096;   // [32 s][128 wo]
  int tid = threadIdx.x, wo = tid & 127, nh = tid >> 7;
  float s = 0.f, s2 = 0.f;
  for(int n = nh; n < 64; n += 2){
    int bn = b*64 + n;
    float w0 = wgt[bn*2], w1 = wgt[bn*2+1];
    int i0 = idx[bn*2], i1 = idx[bn*2+1];
    float y = w0 * b2f(zb[i0*128 + wo]) + w1 * b2f(zb[i1*128 + wo]);
    s += y; s2 += y*y;
  }
  #pragma unroll
  for(int off=32; off; off>>=1){ s += __shfl_down(s, off); s2 += __shfl_down(s2, off); }
  __shared__ float ps[4], ps2[4];
  int wave = tid >> 6, lane = tid & 63;
  if(lane == 0){ ps[wave] = s; ps2[wave] = s2; }
  __syncthreads();
  if(tid == 0){
    atomicAdd(&stats[o*2],   ps[0]+ps[1]+ps[2]+ps[3]);
    atomicAdd(&stats[o*2+1], ps2[0]+ps2[1]+ps2[2]+ps2[3]);
  }
}

// ---------------- K7: dense normalize + ReLU -> d_out (f32) -------------------
__global__ __launch_bounds__(256) void k_dout(const ushort* __restrict__ z,
    const int* __restrict__ idx, const float* __restrict__ wgt,
    const float* __restrict__ stats, const float* __restrict__ gam,
    const float* __restrict__ bet, float* __restrict__ out){
  int blk = blockIdx.x; int b = blk >> 7, o = blk & 127;
  const float N = 262144.f;
  float mu = stats[o*2] / N;
  float var = fmaxf(stats[o*2+1] / N - mu*mu, 0.f);
  float a = gam[o] * rsqrtf(var + 1e-5f);
  float be = bet[o];
  const ushort* zb = z + (size_t)(b*128 + o) * 4096;
  float* ob = out + 1048576 + (size_t)(b*128 + o) * 8192;   // [n 64][wo 128]
  int tid = threadIdx.x, wo = tid & 127, nh = tid >> 7;
  for(int n = nh; n < 64; n += 2){
    int bn = b*64 + n;
    float w0 = wgt[bn*2], w1 = wgt[bn*2+1];
    int i0 = idx[bn*2], i1 = idx[bn*2+1];
    float y = w0 * b2f(zb[i0*128 + wo]) + w1 * b2f(zb[i1*128 + wo]);
    ob[n*128 + wo] = relu(a * (y - mu) + be);
  }
}

extern "C" void kernel_launch(void* const* d_in, const int* in_sizes, int n_in,
                              void* d_out, int out_size, void* d_ws, size_t ws_size,
                              hipStream_t stream) {
  (void)in_sizes; (void)n_in; (void)out_size; (void)ws_size;
  const float* sparse_fea = (const float*)d_in[0];
  const float* dense_fea  = (const float*)d_in[1];
  const float* stk_coor   = (const float*)d_in[2];
  const float* stk_bef    = (const float*)d_in[3];
  const float* sp_w   = (const float*)d_in[4];
  const float* sp_b   = (const float*)d_in[5];
  const float* sp_g   = (const float*)d_in[6];
  const float* sp_be  = (const float*)d_in[7];
  const float* ct_w   = (const float*)d_in[8];
  const float* ct_b   = (const float*)d_in[9];
  const float* bn_g   = (const float*)d_in[10];
  const float* bn_be  = (const float*)d_in[11];
  float* out = (float*)d_out;

  char* ws = (char*)d_ws;
  int*    idx    = (int*)   (ws + 0);          //  16 KB
  float*  wgt    = (float*) (ws + 16384);      //  16 KB
  float*  sstats = (float*) (ws + 32768);      //   4 KB (512 o x {sum,sumsq})
  float*  dstats = (float*) (ws + 36864);      //   1 KB (128 o x {sum,sumsq})
  ushort* Aev    = (ushort*)(ws + 40960);      // 128 KB
  ushort* Aod    = (ushort*)(ws + 172032);     // 128 KB
  ushort* spwb   = (ushort*)(ws + 303104);     //   1 MB (sp_w bf16)
  ushort* spiT   = (ushort*)(ws + 1351680);    //   4 MB
  float*  h      = (float*) (ws + 5545984);    //   4 MB
  ushort* z      = (ushort*)(ws + 9740288);    //  32 MB  (total ~43.3 MB)

  hipMemsetAsync(ws + 32768, 0, 8192, stream);  // re-zero BN accumulators every launch
  hipLaunchKernelGGL(k_prep,   dim3(776),  dim3(256), 0, stream,
                     sp_w, spwb, ct_w, Aev, Aod, stk_bef, stk_coor, idx, wgt);
  hipLaunchKernelGGL(k_spiT,   dim3(2048), dim3(256), 0, stream, sparse_fea, idx, wgt, spiT);
  hipLaunchKernelGGL(k_sgemm,  dim3(512),  dim3(256), 0, stream, spwb, spiT, sp_b, h, sstats);
  hipLaunchKernelGGL(k_sbn,    dim3(512),  dim3(256), 0, stream, h, sstats, sp_g, sp_be, out);
  hipLaunchKernelGGL(k_conv,   dim3(1024), dim3(256), 0, stream, dense_fea, Aev, Aod, ct_b, z);
  hipLaunchKernelGGL(k_dstats, dim3(4096), dim3(256), 0, stream, z, idx, wgt, dstats);
  hipLaunchKernelGGL(k_dout,   dim3(4096), dim3(256), 0, stream, z, idx, wgt, dstats, bn_g, bn_be, out);
}

// Round 4
// 219.377 us; speedup vs baseline: 1.3584x; 1.1754x over previous
//
#include <hip/hip_runtime.h>
#include <hip/hip_bf16.h>

typedef __attribute__((ext_vector_type(8))) short short8;
typedef __attribute__((ext_vector_type(4))) float f32x4;
typedef __attribute__((ext_vector_type(16))) float f32x16;

#define MFMA16(a,b,c) __builtin_amdgcn_mfma_f32_16x16x32_bf16((a),(b),(c),0,0,0)
#define MFMA32(a,b,c) __builtin_amdgcn_mfma_f32_32x32x16_bf16((a),(b),(c),0,0,0)

static __device__ __forceinline__ float b2f(ushort u){
  union { unsigned u32; float f; } x; x.u32 = ((unsigned)u) << 16; return x.f;
}
static __device__ __forceinline__ ushort f2b(float f){
  union { float f; unsigned u; } x; x.f = f;
  unsigned r = x.u + 0x7fffu + ((x.u >> 16) & 1u);
  return (ushort)(r >> 16);
}
// NaN-PROPAGATING relu (fmaxf(NaN,0)==0 would mask upstream NaNs)
static __device__ __forceinline__ float relu(float v){ return (v <= 0.f) ? 0.f : v; }

// ---------------- K1: fused prep: sp_w->bf16 panel | A panels | kNN ----------
// Panel layouts (all bf16):
//   spwb : [kblk=k/8 (128)][o (512)][8]   flat = (k>>3)*4096 + o*8 + (k&7)
//   Aev/Aod : [kblk (64)][o (128)][8]     flat = (kc>>3)*1024 + o*8 + (kc&7)
__global__ __launch_bounds__(256) void k_prep(
    const float* __restrict__ spw, ushort* __restrict__ spwb,
    const float* __restrict__ ctw, ushort* __restrict__ Aev, ushort* __restrict__ Aod,
    const float* __restrict__ bef, const float* __restrict__ coor,
    int* __restrict__ idx, float* __restrict__ wgt){
  int blk = blockIdx.x, tid = threadIdx.x;
  if(blk < 512){
    int i = blk*256 + tid;                  // float4 index, 131072 total
    int o = i >> 8;                         // sp_w is [512 o][1024 k]
    int k = (i & 255) * 4;
    float4 v = ((const float4*)spw)[i];
    ushort4 ov; ov.x=f2b(v.x); ov.y=f2b(v.y); ov.z=f2b(v.z); ov.w=f2b(v.w);
    *(ushort4*)(spwb + (size_t)(k>>3)*4096 + o*8 + (k&7)) = ov;
  } else if(blk < 768){
    int i = (blk-512)*256 + tid;            // 65536 = o*512 + kc
    int o = i >> 9, kc = i & 511;
    int c = kc & 255, hi = kc >> 8;
    const float* w = ctw + ((size_t)c*128 + o)*4;   // [in 256][out 128][1][4]
    int j = ((kc>>3)<<10) + (o<<3) + (kc&7);
    Aev[j] = f2b(w[hi ? 3 : 1]);            // A_even = [kw1 ; kw3]
    Aod[j] = f2b(w[hi ? 2 : 0]);            // A_odd  = [kw0 ; kw2]
  } else {
    int t = (blk-768)*256 + tid;            // 0..2047 = b*64+n
    int b = t >> 6;
    float v[32]; float sb = 0.f;
    const float* br = bef + (size_t)t * 32;
    #pragma unroll
    for(int c=0;c<32;c++){ float x = br[c]; v[c] = x; sb += x*x; }
    float d0 = 1e30f, d1 = 1e30f; int i0 = 0, i1 = 0;
    const float* cr = coor + (size_t)b * 1024;
    for(int m=0;m<32;m++){
      float dot = 0.f, sc = 0.f;
      #pragma unroll
      for(int c=0;c<32;c++){ float x = cr[m*32+c]; dot += v[c]*x; sc += x*x; }
      float d = sb + sc - 2.f*dot;
      if(d < d0){ d1 = d0; i1 = i0; d0 = d; i0 = m; }   // strict < keeps lowest idx on ties
      else if(d < d1){ d1 = d; i1 = m; }
    }
    float r0 = 1.f/(d0 + 1e-8f), r1 = 1.f/(d1 + 1e-8f);
    float sum = r0 + r1;
    idx[t*2] = i0; idx[t*2+1] = i1;
    wgt[t*2] = r0/sum; wgt[t*2+1] = r1/sum;
  }
}

// ---------------- K2: sparse interp -> spiT panel [b][kblk 128][n 64][8] ------
// block = b*8 + cchunk (128 c's each); LDS stage [128 c][32 m] f32 pad 33.
__global__ __launch_bounds__(256) void k_spiT(const float* __restrict__ sf,
    const int* __restrict__ idx, const float* __restrict__ wgt, ushort* __restrict__ pan){
  __shared__ float Ls[128*33];
  int blk = blockIdx.x; int b = blk >> 3, c0 = (blk & 7) * 128;
  int tid = threadIdx.x;
  const float* src = sf + (size_t)b*32768 + (size_t)c0*32;   // [c][32 m]
  #pragma unroll
  for(int it=0; it<4; ++it){
    int q = it*256 + tid;        // float4 id, 1024 total
    int c = q >> 3, m = (q & 7)*4;
    float4 v = *(const float4*)(src + c*32 + m);
    Ls[c*33+m] = v.x; Ls[c*33+m+1] = v.y; Ls[c*33+m+2] = v.z; Ls[c*33+m+3] = v.w;
  }
  __syncthreads();
  int n = tid & 63, ob = tid >> 6;
  int bn = b*64 + n;
  int i0 = idx[bn*2], i1 = idx[bn*2+1];
  float w0 = wgt[bn*2], w1 = wgt[bn*2+1];
  ushort* dst = pan + (size_t)b*65536 + n*8;
  #pragma unroll
  for(int it=0; it<4; ++it){
    int oct = ob + it*4;                 // 0..15 (8 c's each)
    short8 ov;
    #pragma unroll
    for(int j=0;j<8;j++){
      int c = oct*8 + j;
      ov[j] = (short)f2b(w0*Ls[c*33+i0] + w1*Ls[c*33+i1]);
    }
    *(short8*)(dst + (size_t)((c0>>3) + oct)*512) = ov;   // 64-lane contiguous 1KB store
  }
}

// ---------------- K3: sparse GEMM h = sp_w @ spiT + bias, fused stat atomics --
// 512 blocks: b(32) x og(8) x nh(2); block covers 64 o x 32 n; panel operands
__global__ __launch_bounds__(256) void k_sgemm(const ushort* __restrict__ spw,
    const ushort* __restrict__ spiT, const float* __restrict__ spb,
    float* __restrict__ h, float* __restrict__ sstats){
  int blk = blockIdx.x;
  int b = blk >> 4, og = (blk >> 1) & 7, nh = blk & 1;
  int wave = threadIdx.x >> 6, lane = threadIdx.x & 63;
  int lo = lane & 15, hi = lane >> 4;
  int o0 = og*64 + wave*16;
  const short* A = (const short*)spw  + (size_t)hi*4096 + (o0 + lo)*8;
  const short* B = (const short*)spiT + (size_t)b*65536 + (size_t)hi*512 + (nh*32 + lo)*8;
  f32x4 acc[2] = {};
  for(int k0 = 0; k0 < 1024; k0 += 32){
    int kb = k0 >> 3;
    short8 a = *(const short8*)(A + (size_t)kb*4096);
    #pragma unroll
    for(int q=0;q<2;q++){
      short8 bb = *(const short8*)(B + (size_t)kb*512 + q*128);
      acc[q] = MFMA16(a, bb, acc[q]);
    }
  }
  float sv[4], sv2[4], bias[4];
  #pragma unroll
  for(int r=0;r<4;r++){ sv[r]=0.f; sv2[r]=0.f; bias[r] = spb[o0 + hi*4 + r]; }
  #pragma unroll
  for(int q=0;q<2;q++){
    int n = nh*32 + q*16 + lo;
    #pragma unroll
    for(int r=0;r<4;r++){
      int o = o0 + hi*4 + r;
      float val = acc[q][r] + bias[r];
      h[(size_t)o*2048 + b*64 + n] = val;
      sv[r] += val; sv2[r] += val*val;
    }
  }
  #pragma unroll
  for(int r=0;r<4;r++){
    #pragma unroll
    for(int off=1; off<16; off<<=1){
      sv[r]  += __shfl_xor(sv[r],  off);
      sv2[r] += __shfl_xor(sv2[r], off);
    }
  }
  if(lo == 0){
    #pragma unroll
    for(int r=0;r<4;r++){
      int o = o0 + hi*4 + r;
      atomicAdd(&sstats[o*2],   sv[r]);
      atomicAdd(&sstats[o*2+1], sv2[r]);
    }
  }
}

// ---------------- K4: sparse BN normalize + ReLU -> d_out (single pass) -------
__global__ __launch_bounds__(256) void k_sbn(const float* __restrict__ h,
    const float* __restrict__ sstats, const float* __restrict__ gam,
    const float* __restrict__ bet, float* __restrict__ out){
  int o = blockIdx.x;
  float mu = sstats[o*2] / 2048.f;
  float var = fmaxf(sstats[o*2+1] / 2048.f - mu*mu, 0.f);
  float a = gam[o] * rsqrtf(var + 1e-5f);
  float be = bet[o];
  const float* row = h + (size_t)o * 2048;
  #pragma unroll
  for(int it=0; it<2; ++it){
    int j = it*1024 + threadIdx.x*4;
    float4 v = *(const float4*)(row + j);
    float4 r;
    r.x = relu(a*(v.x-mu)+be); r.y = relu(a*(v.y-mu)+be);
    r.z = relu(a*(v.z-mu)+be); r.w = relu(a*(v.w-mu)+be);
    int b = j >> 6, n = j & 63;
    *(float4*)(out + ((size_t)b*512 + o)*64 + n) = r;
  }
}

// ---------------- K5: fused transpose + ConvTranspose GEMMs + z repack --------
// block=(b,s). LDS L[66 rows][256 c] bf16, rows 0&65 zero, swizzle byte^=((row>>2)&7)<<4.
// A panels: [kblk][o 128][8]. Wave=(parity pe, t-tile tt); B-frag reused over 4 o-tiles.
__global__ __launch_bounds__(256) void k_conv(const float* __restrict__ df,
    const ushort* __restrict__ Aev, const ushort* __restrict__ Aod,
    const float* __restrict__ ctb, ushort* __restrict__ z){
  __shared__ ushort L[66*256];   // 33792 B
  int bs_ = blockIdx.x; int b = bs_ >> 5, s = bs_ & 31;
  int tid = threadIdx.x;

  { // zero boundary rows 0 and 65
    unsigned* Lw = (unsigned*)L;
    int i = (tid < 128) ? tid : (65*128 + (tid - 128));
    Lw[i] = 0u;
  }
  // stage + transpose + f32->bf16
  const float* src = df + ((size_t)(b*256)*32 + s)*64;   // + c*2048 + p
  for(int it=0; it<16; ++it){
    int c = it*16 + (tid>>4);
    float4 v = *(const float4*)(src + (size_t)c*2048 + (tid&15)*4);
    int p0 = (tid&15)*4;
    #pragma unroll
    for(int j=0;j<4;j++){
      int row = p0 + j + 1;
      float fv = (j==0)?v.x:(j==1)?v.y:(j==2)?v.z:v.w;
      *(ushort*)((char*)L + row*512 + ((2*c) ^ (((row>>2)&7)<<4))) = f2b(fv);
    }
  }
  __syncthreads();

  int wave = tid >> 6, lane = tid & 63;
  int pe = wave >> 1, tt = wave & 1;     // parity, t-tile
  int tcol = lane & 31;
  int t = tt*32 + tcol;
  int kl = (lane >> 5) * 8;              // k sub-group for LDS B-frag
  const short* A = (const short*)(pe ? Aod : Aev) + (size_t)(lane>>5)*1024 + tcol*8;
  f32x16 acc[4] = {};
  #pragma unroll
  for(int hf=0; hf<2; ++hf){
    int rowr = t + (hf==0 ? 1 : 0) + pe;       // source L-row for this parity/half
    const char* Lr = (const char*)L + rowr*512;
    int swz = ((rowr>>2)&7) << 4;
    for(int k0=0; k0<256; k0+=16){
      short8 bfrag = *(const short8*)(Lr + ((2*(k0+kl)) ^ swz));
      const short* Ab = A + (size_t)((hf*256 + k0) >> 3)*1024;
      #pragma unroll
      for(int ot=0; ot<4; ++ot){
        short8 afrag = *(const short8*)(Ab + ot*256);   // 2x512B contiguous segments
        acc[ot] = MFMA32(afrag, bfrag, acc[ot]);
      }
    }
  }
  __syncthreads();   // all waves done reading L before repack overwrite

  // repack via LDS: Z[o 128][wo 128] bf16 (32 KB, reuse L)
  #pragma unroll
  for(int ot=0; ot<4; ++ot){
    #pragma unroll
    for(int r=0;r<16;r++){
      int o = ot*32 + (r&3) + 8*(r>>2) + 4*(lane>>5);
      L[o*128 + 2*t + pe] = f2b(acc[ot][r] + ctb[o]);
    }
  }
  __syncthreads();
  // linear coalesced store: z[b][o][s][wo]
  ushort* zb = z + ((size_t)(b*128)*32 + s)*128;
  #pragma unroll
  for(int it=0; it<8; ++it){
    int q = it*256 + tid;          // short8 chunk, 2048 total
    int o = q >> 4, w0 = (q & 15)*8;
    *(short8*)(zb + (size_t)o*4096 + w0) = *(const short8*)(L + o*128 + w0);
  }
}

// ---------------- K6: dense BN batch stats over interpolated y ----------------
__global__ __launch_bounds__(256) void k_dstats(const ushort* __restrict__ z,
    const int* __restrict__ idx, const float* __restrict__ wgt, float* __restrict__ stats){
  int blk = blockIdx.x; int b = blk >> 7, o = blk & 127;
  const ushort* zb = z + (size_t)(b*128 + o) * 4096;   // [32 s][128 wo]
  int tid = threadIdx.x, wo = tid & 127, nh = tid >> 7;
  float s = 0.f, s2 = 0.f;
  for(int n = nh; n < 64; n += 2){
    int bn = b*64 + n;
    float w0 = wgt[bn*2], w1 = wgt[bn*2+1];
    int i0 = idx[bn*2], i1 = idx[bn*2+1];
    float y = w0 * b2f(zb[i0*128 + wo]) + w1 * b2f(zb[i1*128 + wo]);
    s += y; s2 += y*y;
  }
  #pragma unroll
  for(int off=32; off; off>>=1){ s += __shfl_down(s, off); s2 += __shfl_down(s2, off); }
  __shared__ float ps[4], ps2[4];
  int wave = tid >> 6, lane = tid & 63;
  if(lane == 0){ ps[wave] = s; ps2[wave] = s2; }
  __syncthreads();
  if(tid == 0){
    atomicAdd(&stats[o*2],   ps[0]+ps[1]+ps[2]+ps[3]);
    atomicAdd(&stats[o*2+1], ps2[0]+ps2[1]+ps2[2]+ps2[3]);
  }
}

// ---------------- K7: dense normalize + ReLU -> d_out (f32) -------------------
__global__ __launch_bounds__(256) void k_dout(const ushort* __restrict__ z,
    const int* __restrict__ idx, const float* __restrict__ wgt,
    const float* __restrict__ stats, const float* __restrict__ gam,
    const float* __restrict__ bet, float* __restrict__ out){
  int blk = blockIdx.x; int b = blk >> 7, o = blk & 127;
  const float N = 262144.f;
  float mu = stats[o*2] / N;
  float var = fmaxf(stats[o*2+1] / N - mu*mu, 0.f);
  float a = gam[o] * rsqrtf(var + 1e-5f);
  float be = bet[o];
  const ushort* zb = z + (size_t)(b*128 + o) * 4096;
  float* ob = out + 1048576 + (size_t)(b*128 + o) * 8192;   // [n 64][wo 128]
  int tid = threadIdx.x, wo = tid & 127, nh = tid >> 7;
  for(int n = nh; n < 64; n += 2){
    int bn = b*64 + n;
    float w0 = wgt[bn*2], w1 = wgt[bn*2+1];
    int i0 = idx[bn*2], i1 = idx[bn*2+1];
    float y = w0 * b2f(zb[i0*128 + wo]) + w1 * b2f(zb[i1*128 + wo]);
    ob[n*128 + wo] = relu(a * (y - mu) + be);
  }
}

extern "C" void kernel_launch(void* const* d_in, const int* in_sizes, int n_in,
                              void* d_out, int out_size, void* d_ws, size_t ws_size,
                              hipStream_t stream) {
  (void)in_sizes; (void)n_in; (void)out_size; (void)ws_size;
  const float* sparse_fea = (const float*)d_in[0];
  const float* dense_fea  = (const float*)d_in[1];
  const float* stk_coor   = (const float*)d_in[2];
  const float* stk_bef    = (const float*)d_in[3];
  const float* sp_w   = (const float*)d_in[4];
  const float* sp_b   = (const float*)d_in[5];
  const float* sp_g   = (const float*)d_in[6];
  const float* sp_be  = (const float*)d_in[7];
  const float* ct_w   = (const float*)d_in[8];
  const float* ct_b   = (const float*)d_in[9];
  const float* bn_g   = (const float*)d_in[10];
  const float* bn_be  = (const float*)d_in[11];
  float* out = (float*)d_out;

  char* ws = (char*)d_ws;
  int*    idx    = (int*)   (ws + 0);          //  16 KB
  float*  wgt    = (float*) (ws + 16384);      //  16 KB
  float*  sstats = (float*) (ws + 32768);      //   4 KB (512 o x {sum,sumsq})
  float*  dstats = (float*) (ws + 36864);      //   1 KB (128 o x {sum,sumsq})
  ushort* Aev    = (ushort*)(ws + 40960);      // 128 KB (panel)
  ushort* Aod    = (ushort*)(ws + 172032);     // 128 KB (panel)
  ushort* spwb   = (ushort*)(ws + 303104);     //   1 MB (sp_w bf16 panel)
  ushort* spiT   = (ushort*)(ws + 1351680);    //   4 MB (panel)
  float*  h      = (float*) (ws + 5545984);    //   4 MB
  ushort* z      = (ushort*)(ws + 9740288);    //  32 MB  (total ~43.3 MB)

  hipMemsetAsync(ws + 32768, 0, 8192, stream);  // re-zero BN accumulators every launch
  hipLaunchKernelGGL(k_prep,   dim3(776),  dim3(256), 0, stream,
                     sp_w, spwb, ct_w, Aev, Aod, stk_bef, stk_coor, idx, wgt);
  hipLaunchKernelGGL(k_spiT,   dim3(256),  dim3(256), 0, stream, sparse_fea, idx, wgt, spiT);
  hipLaunchKernelGGL(k_sgemm,  dim3(512),  dim3(256), 0, stream, spwb, spiT, sp_b, h, sstats);
  hipLaunchKernelGGL(k_sbn,    dim3(512),  dim3(256), 0, stream, h, sstats, sp_g, sp_be, out);
  hipLaunchKernelGGL(k_conv,   dim3(1024), dim3(256), 0, stream, dense_fea, Aev, Aod, ct_b, z);
  hipLaunchKernelGGL(k_dstats, dim3(4096), dim3(256), 0, stream, z, idx, wgt, dstats);
  hipLaunchKernelGGL(k_dout,   dim3(4096), dim3(256), 0, stream, z, idx, wgt, dstats, bn_g, bn_be, out);
}